// Round 6
// baseline (328.141 us; speedup 1.0000x reference)
//
#include <hip/hip_runtime.h>
#include <hip/hip_bf16.h>
#include <stdint.h>

// Problem constants (f32 I/O; bf16 internal compute)
constexpr int Hh = 16, Ll = 1024, Dd = 1024, DHh = 64, CL = 1024, TKV = 2048;
constexpr size_t OUT_ELEMS = 4ull * 1024 * 1024;   // B*L*D = 4,194,304 floats

typedef __attribute__((ext_vector_type(8))) short short8;
typedef __attribute__((ext_vector_type(4))) float floatx4;

#define MFMA16(a, b, c) __builtin_amdgcn_mfma_f32_16x16x32_bf16(a, b, c, 0, 0, 0)

__device__ __forceinline__ short bfs(float x) {
    union { __hip_bfloat16 h; short s; } u;
    u.h = __float2bfloat16(x);
    return u.s;
}

__device__ __forceinline__ short8 cvt8(const float* p) {
    float4 a = *(const float4*)p;
    float4 b = *(const float4*)(p + 4);
    short8 r;
    r[0] = bfs(a.x); r[1] = bfs(a.y); r[2] = bfs(a.z); r[3] = bfs(a.w);
    r[4] = bfs(b.x); r[5] = bfs(b.y); r[6] = bfs(b.z); r[7] = bfs(b.w);
    return r;
}

// ---------------------------------------------------------------------------
// Kernel 1: exact f32 copy of old cache into new_cache[t < CL]
// ---------------------------------------------------------------------------
__global__ __launch_bounds__(256) void copy_cache_kernel(
    const float* __restrict__ cache, float* __restrict__ outc) {
    int c = blockIdx.x * 256 + threadIdx.x;   // 1,048,576 chunks of 8 floats
    int bh  = c >> 14;                        // 16384 chunks per (b,h)
    int rem = c & 16383;
    const float* s = cache + (size_t)c * 8;
    float* d = outc + OUT_ELEMS + (size_t)bh * 262144 + (size_t)rem * 8;
    *(float4*)d       = *(const float4*)s;
    *(float4*)(d + 4) = *(const float4*)(s + 4);
}

// ---------------------------------------------------------------------------
// GEMM: C(4096,1024) = A(4096,1024) @ W(1024,1024)^T + bias
// MODE 0: A = bf16 workspace (attn out), C = f32 d_out[0:OUT_ELEMS]
// MODE 1: A = f32 query, C = bf16 Q workspace (B,H,L,DH)
// MODE 2: A = f32 key,   C = f32 new_cache [b,h,CL+l, 0:64]
// MODE 3: A = f32 value, C = f32 new_cache [b,h,CL+l, 64:128]
// ---------------------------------------------------------------------------
template <int MODE>
__global__ __launch_bounds__(256) void gemm_nt(
    const void* __restrict__ Av, const float* __restrict__ W,
    const float* __restrict__ bias, void* __restrict__ Cv) {
    constexpr int K = 1024, BK = 64;
    __shared__ alignas(16) __hip_bfloat16 As[128 * BK];
    __shared__ alignas(16) __hip_bfloat16 Bs[128 * BK];

    const int tid = threadIdx.x;
    const int w = tid >> 6, lane = tid & 63;
    const int g = lane >> 4, lr = lane & 15;
    const int tm = blockIdx.x * 128, tn = blockIdx.y * 128;
    const int wr = (w >> 1) * 64, wc = (w & 1) * 64;

    floatx4 acc[4][4] = {};

    for (int k0 = 0; k0 < K; k0 += BK) {
        __syncthreads();
#pragma unroll
        for (int i = 0; i < 4; i++) {
            int c = i * 256 + tid;            // 1024 chunks of 8 elems per tile
            int row = c >> 3, colc = (c & 7) * 8;
            if (MODE == 0) {
                const __hip_bfloat16* A = (const __hip_bfloat16*)Av;
                *(short8*)&As[row * BK + colc] =
                    *(const short8*)(A + (size_t)(tm + row) * K + k0 + colc);
            } else {
                const float* A = (const float*)Av;
                *(short8*)&As[row * BK + colc] = cvt8(A + (size_t)(tm + row) * K + k0 + colc);
            }
            *(short8*)&Bs[row * BK + colc] = cvt8(W + (size_t)(tn + row) * K + k0 + colc);
        }
        __syncthreads();
#pragma unroll
        for (int kk = 0; kk < 2; kk++) {
            short8 af[4], bf[4];
#pragma unroll
            for (int i = 0; i < 4; i++)
                af[i] = *(const short8*)&As[(wr + i * 16 + lr) * BK + kk * 32 + g * 8];
#pragma unroll
            for (int j = 0; j < 4; j++)
                bf[j] = *(const short8*)&Bs[(wc + j * 16 + lr) * BK + kk * 32 + g * 8];
#pragma unroll
            for (int i = 0; i < 4; i++)
#pragma unroll
                for (int j = 0; j < 4; j++)
                    acc[i][j] = MFMA16(af[i], bf[j], acc[i][j]);
        }
    }

    // Epilogue: bias + mode-specific scatter (f32 except MODE 1 -> bf16 ws)
#pragma unroll
    for (int j = 0; j < 4; j++) {
        int n = tn + wc + j * 16 + lr;
        float bv = bias[n];
#pragma unroll
        for (int i = 0; i < 4; i++) {
#pragma unroll
            for (int r = 0; r < 4; r++) {
                int m = tm + wr + i * 16 + g * 4 + r;
                float v = acc[i][j][r] + bv;
                if (MODE == 0) {
                    ((float*)Cv)[(size_t)m * 1024 + n] = v;
                } else if (MODE == 1) {
                    size_t addr = (size_t)(m >> 10) * ((size_t)Hh * Ll * DHh) +
                                  (size_t)(n >> 6) * ((size_t)Ll * DHh) +
                                  (size_t)(m & 1023) * DHh + (n & 63);
                    ((__hip_bfloat16*)Cv)[addr] = __float2bfloat16(v);
                } else {
                    size_t bh = (size_t)((m >> 10) * Hh + (n >> 6));
                    size_t addr = OUT_ELEMS + (bh * TKV + CL + (m & 1023)) * 128 + (n & 63) +
                                  (MODE == 3 ? 64 : 0);
                    ((float*)Cv)[addr] = v;
                }
            }
        }
    }
}

// ---------------------------------------------------------------------------
// Flash attention: grid (L/64, B*H), 256 threads = 4 waves, wave owns 16 q-rows.
// KVBLK=128. Q from bf16 ws (B,H,L,DH); K/V from f32 new_cache.
// K staged row-major [128][72]; V staged transposed Vt[d][t^swz] (XOR-swizzled,
// conflict-free scalar stores AND b128 reads). O -> bf16 ws (B,L,D).
// ---------------------------------------------------------------------------
__global__ __launch_bounds__(256) void attn_kernel(
    const __hip_bfloat16* __restrict__ qws, const float* __restrict__ kv,
    __hip_bfloat16* __restrict__ ows) {
    constexpr int KVB = 128;
    __shared__ alignas(16) __hip_bfloat16 Ks[KVB * 72];      // 18432 B
    __shared__ alignas(16) __hip_bfloat16 Vt[64 * KVB];      // 16384 B  [d][t^swz]
    __shared__ alignas(16) __hip_bfloat16 Ps[4][16 * 136];   // 17408 B

    const int tid = threadIdx.x;
    const int w = tid >> 6, lane = tid & 63;
    const int g = lane >> 4, lr = lane & 15;
    const int bh = blockIdx.y;            // b*16 + h
    const int q0 = blockIdx.x * 64 + w * 16;

    const __hip_bfloat16* qbase = qws + (size_t)bh * Ll * DHh;
    const float* kvb = kv + (size_t)bh * TKV * 128;

    short8 qf[2];
#pragma unroll
    for (int kk = 0; kk < 2; kk++)
        qf[kk] = *(const short8*)(qbase + (size_t)(q0 + lr) * DHh + kk * 32 + g * 8);

    float rm[4], rl[4];
    floatx4 o[4] = {};
#pragma unroll
    for (int j = 0; j < 4; j++) { rm[j] = -3e38f; rl[j] = 0.f; }

    for (int t0 = 0; t0 < TKV; t0 += KVB) {
        __syncthreads();
        // stage K [t][72 pad] (vector) and V^T swizzled (scalar, conflict-free)
#pragma unroll
        for (int it = 0; it < 4; it++) {
            int c = it * 256 + tid;           // 0..1023
            int t = c >> 3, off = (c & 7) * 8;
            const float* gp = kvb + (size_t)(t0 + t) * 128;
            *(short8*)&Ks[t * 72 + off] = cvt8(gp + off);
            float4 v0 = *(const float4*)(gp + 64 + off);
            float4 v1 = *(const float4*)(gp + 64 + off + 4);
            float vv[8] = {v0.x, v0.y, v0.z, v0.w, v1.x, v1.y, v1.z, v1.w};
#pragma unroll
            for (int e = 0; e < 8; e++) {
                int d = off + e;
                int sw = ((d >> 3) ^ d) & 7;
                ((short*)Vt)[d * KVB + (t ^ (sw << 3))] = bfs(vv[e]);
            }
        }
        __syncthreads();

        // S = (Q @ K^T) / 8 : 8 col-blocks of 16 kv each
        floatx4 s[8];
#pragma unroll
        for (int f = 0; f < 8; f++) {
            floatx4 z = {};
#pragma unroll
            for (int kk = 0; kk < 2; kk++) {
                short8 bfr = *(const short8*)&Ks[(f * 16 + lr) * 72 + kk * 32 + g * 8];
                z = MFMA16(qf[kk], bfr, z);
            }
            s[f] = z * 0.125f;
        }

        // online softmax: q-row r = g*4 + j lives on the 16 lanes of group g
        float mt[4];
#pragma unroll
        for (int j = 0; j < 4; j++) {
            float mv = fmaxf(fmaxf(fmaxf(s[0][j], s[1][j]), fmaxf(s[2][j], s[3][j])),
                             fmaxf(fmaxf(s[4][j], s[5][j]), fmaxf(s[6][j], s[7][j])));
            mv = fmaxf(mv, __shfl_xor(mv, 1));
            mv = fmaxf(mv, __shfl_xor(mv, 2));
            mv = fmaxf(mv, __shfl_xor(mv, 4));
            mv = fmaxf(mv, __shfl_xor(mv, 8));
            mt[j] = mv;
        }
        float corr[4];
#pragma unroll
        for (int j = 0; j < 4; j++) {
            float mn = fmaxf(rm[j], mt[j]);
            corr[j] = __expf(rm[j] - mn);
            rm[j] = mn;
        }
        float rs[4] = {0.f, 0.f, 0.f, 0.f};
#pragma unroll
        for (int f = 0; f < 8; f++)
#pragma unroll
            for (int j = 0; j < 4; j++) {
                float p = __expf(s[f][j] - rm[j]);
                s[f][j] = p;
                rs[j] += p;
            }
#pragma unroll
        for (int j = 0; j < 4; j++) {
            rs[j] += __shfl_xor(rs[j], 1);
            rs[j] += __shfl_xor(rs[j], 2);
            rs[j] += __shfl_xor(rs[j], 4);
            rs[j] += __shfl_xor(rs[j], 8);
            rl[j] = rl[j] * corr[j] + rs[j];
#pragma unroll
            for (int f2 = 0; f2 < 4; f2++) o[f2][j] = o[f2][j] * corr[j];
        }

        // P -> LDS (per-wave region)
        __hip_bfloat16* pw = &Ps[w][0];
#pragma unroll
        for (int f = 0; f < 8; f++)
#pragma unroll
            for (int j = 0; j < 4; j++)
                pw[(g * 4 + j) * 136 + f * 16 + lr] = __float2bfloat16(s[f][j]);

        // PV: A = P (rows=q), B = V^T rows (swizzled b128 reads, conflict-free)
#pragma unroll
        for (int kk = 0; kk < 4; kk++) {
            short8 pa = *(const short8*)&pw[lr * 136 + kk * 32 + g * 8];
#pragma unroll
            for (int f2 = 0; f2 < 4; f2++) {
                int d = f2 * 16 + lr;
                int sw = ((d >> 3) ^ d) & 7;
                short8 vb = *(const short8*)&Vt[d * KVB + ((kk * 32 + g * 8) ^ (sw << 3))];
                o[f2] = MFMA16(pa, vb, o[f2]);
            }
        }
    }

    // Epilogue: normalize and store bf16 to (B,L,D) workspace
    const int b = bh >> 4, h = bh & 15;
#pragma unroll
    for (int j = 0; j < 4; j++) {
        float inv = 1.0f / rl[j];
        int qrow = q0 + g * 4 + j;
        size_t rb = ((size_t)b * Ll + qrow) * Dd + (size_t)h * DHh;
#pragma unroll
        for (int f2 = 0; f2 < 4; f2++)
            ows[rb + f2 * 16 + lr] = __float2bfloat16(o[f2][j] * inv);
    }
}

// ---------------------------------------------------------------------------
extern "C" void kernel_launch(void* const* d_in, const int* in_sizes, int n_in,
                              void* d_out, int out_size, void* d_ws, size_t ws_size,
                              hipStream_t stream) {
    (void)in_sizes; (void)n_in; (void)out_size; (void)ws_size;
    const float* query = (const float*)d_in[0];
    const float* key   = (const float*)d_in[1];
    const float* value = (const float*)d_in[2];
    const float* cache = (const float*)d_in[3];
    const float* Wq = (const float*)d_in[4];
    const float* bq = (const float*)d_in[5];
    const float* Wk = (const float*)d_in[6];
    const float* bk = (const float*)d_in[7];
    const float* Wv = (const float*)d_in[8];
    const float* bv = (const float*)d_in[9];
    const float* Wo = (const float*)d_in[10];
    const float* bo = (const float*)d_in[11];

    float* out = (float*)d_out;
    __hip_bfloat16* qws = (__hip_bfloat16*)d_ws;          // (B,H,L,DH) bf16, 8 MB
    __hip_bfloat16* aws = qws + OUT_ELEMS;                // (B,L,D)    bf16, 8 MB

    dim3 bb(256);
    copy_cache_kernel<<<dim3(4096), bb, 0, stream>>>(cache, out);

    dim3 gg(32, 8);
    gemm_nt<1><<<gg, bb, 0, stream>>>(query, Wq, bq, qws);
    gemm_nt<2><<<gg, bb, 0, stream>>>(key, Wk, bk, out);
    gemm_nt<3><<<gg, bb, 0, stream>>>(value, Wv, bv, out);

    attn_kernel<<<dim3(16, 64), bb, 0, stream>>>(qws, out + OUT_ELEMS, aws);

    gemm_nt<0><<<gg, bb, 0, stream>>>(aws, Wo, bo, out);
}

// Round 7
// 264.183 us; speedup vs baseline: 1.2421x; 1.2421x over previous
//
#include <hip/hip_runtime.h>
#include <hip/hip_bf16.h>
#include <stdint.h>

// Problem constants (f32 I/O; bf16 internal compute)
constexpr int Hh = 16, Ll = 1024, Dd = 1024, DHh = 64, CL = 1024, TKV = 2048;
constexpr size_t OUT_ELEMS = 4ull * 1024 * 1024;   // B*L*D = 4,194,304 floats

typedef __attribute__((ext_vector_type(8))) short short8;
typedef __attribute__((ext_vector_type(4))) float floatx4;

#define MFMA16(a, b, c) __builtin_amdgcn_mfma_f32_16x16x32_bf16(a, b, c, 0, 0, 0)

__device__ __forceinline__ short bfs(float x) {
    union { __hip_bfloat16 h; short s; } u;
    u.h = __float2bfloat16(x);
    return u.s;
}

__device__ __forceinline__ short8 cvt8(const float* p) {
    float4 a = *(const float4*)p;
    float4 b = *(const float4*)(p + 4);
    short8 r;
    r[0] = bfs(a.x); r[1] = bfs(a.y); r[2] = bfs(a.z); r[3] = bfs(a.w);
    r[4] = bfs(b.x); r[5] = bfs(b.y); r[6] = bfs(b.z); r[7] = bfs(b.w);
    return r;
}

// ---------------------------------------------------------------------------
// Kernel 1: exact f32 copy of old cache into new_cache[t < CL]
// ---------------------------------------------------------------------------
__global__ __launch_bounds__(256) void copy_cache_kernel(
    const float* __restrict__ cache, float* __restrict__ outc) {
    int c = blockIdx.x * 256 + threadIdx.x;   // 1,048,576 chunks of 8 floats
    int bh  = c >> 14;                        // 16384 chunks per (b,h)
    int rem = c & 16383;
    const float* s = cache + (size_t)c * 8;
    float* d = outc + OUT_ELEMS + (size_t)bh * 262144 + (size_t)rem * 8;
    *(float4*)d       = *(const float4*)s;
    *(float4*)(d + 4) = *(const float4*)(s + 4);
}

// ---------------------------------------------------------------------------
// GEMM: C(4096,1024) = A(4096,1024) @ W(1024,1024)^T + bias
// MODE 0: A = bf16 workspace (attn out), C = f32 d_out[0:OUT_ELEMS]
// MODE 1: A = f32 query, C = bf16 Q ws (B,H,L,DH), scaled by 1/8 (QK scale)
// MODE 2: A = f32 key,   C = f32 new_cache [b,h,CL+l, 0:64]
// MODE 3: A = f32 value, C = f32 new_cache [b,h,CL+l, 64:128]
// ---------------------------------------------------------------------------
template <int MODE>
__global__ __launch_bounds__(256) void gemm_nt(
    const void* __restrict__ Av, const float* __restrict__ W,
    const float* __restrict__ bias, void* __restrict__ Cv) {
    constexpr int K = 1024, BK = 64;
    __shared__ alignas(16) __hip_bfloat16 As[128 * BK];
    __shared__ alignas(16) __hip_bfloat16 Bs[128 * BK];

    const int tid = threadIdx.x;
    const int w = tid >> 6, lane = tid & 63;
    const int g = lane >> 4, lr = lane & 15;
    const int tm = blockIdx.x * 128, tn = blockIdx.y * 128;
    const int wr = (w >> 1) * 64, wc = (w & 1) * 64;

    floatx4 acc[4][4] = {};

    for (int k0 = 0; k0 < K; k0 += BK) {
        __syncthreads();
#pragma unroll
        for (int i = 0; i < 4; i++) {
            int c = i * 256 + tid;            // 1024 chunks of 8 elems per tile
            int row = c >> 3, colc = (c & 7) * 8;
            if (MODE == 0) {
                const __hip_bfloat16* A = (const __hip_bfloat16*)Av;
                *(short8*)&As[row * BK + colc] =
                    *(const short8*)(A + (size_t)(tm + row) * K + k0 + colc);
            } else {
                const float* A = (const float*)Av;
                *(short8*)&As[row * BK + colc] = cvt8(A + (size_t)(tm + row) * K + k0 + colc);
            }
            *(short8*)&Bs[row * BK + colc] = cvt8(W + (size_t)(tn + row) * K + k0 + colc);
        }
        __syncthreads();
#pragma unroll
        for (int kk = 0; kk < 2; kk++) {
            short8 af[4], bf[4];
#pragma unroll
            for (int i = 0; i < 4; i++)
                af[i] = *(const short8*)&As[(wr + i * 16 + lr) * BK + kk * 32 + g * 8];
#pragma unroll
            for (int j = 0; j < 4; j++)
                bf[j] = *(const short8*)&Bs[(wc + j * 16 + lr) * BK + kk * 32 + g * 8];
#pragma unroll
            for (int i = 0; i < 4; i++)
#pragma unroll
                for (int j = 0; j < 4; j++)
                    acc[i][j] = MFMA16(af[i], bf[j], acc[i][j]);
        }
    }

    // Epilogue: bias + mode-specific scatter (f32 except MODE 1 -> bf16 ws)
#pragma unroll
    for (int j = 0; j < 4; j++) {
        int n = tn + wc + j * 16 + lr;
        float bv = bias[n];
#pragma unroll
        for (int i = 0; i < 4; i++) {
#pragma unroll
            for (int r = 0; r < 4; r++) {
                int m = tm + wr + i * 16 + g * 4 + r;
                float v = acc[i][j][r] + bv;
                if (MODE == 0) {
                    ((float*)Cv)[(size_t)m * 1024 + n] = v;
                } else if (MODE == 1) {
                    // fold QK^T 1/sqrt(DH)=1/8 scale into Q (exact: power of 2)
                    size_t addr = (size_t)(m >> 10) * ((size_t)Hh * Ll * DHh) +
                                  (size_t)(n >> 6) * ((size_t)Ll * DHh) +
                                  (size_t)(m & 1023) * DHh + (n & 63);
                    ((__hip_bfloat16*)Cv)[addr] = __float2bfloat16(v * 0.125f);
                } else {
                    size_t bh = (size_t)((m >> 10) * Hh + (n >> 6));
                    size_t addr = OUT_ELEMS + (bh * TKV + CL + (m & 1023)) * 128 + (n & 63) +
                                  (MODE == 3 ? 64 : 0);
                    ((float*)Cv)[addr] = v;
                }
            }
        }
    }
}

// ---------------------------------------------------------------------------
// Flash attention: grid (B*H, L/128), 512 threads = 8 waves, wave owns 16 q-rows.
// KVBLK=128, double-buffered via register staging (async-STAGE split):
//   load tile t+1 to regs right after LDS-ready barrier; write at next top.
// K staged row-major [128][72]; V transposed Vt[d][t^swz] (XOR swizzle).
// Q pre-scaled by 1/8. O -> bf16 ws (B,L,D).
// ---------------------------------------------------------------------------
__global__ __launch_bounds__(512) void attn_kernel(
    const __hip_bfloat16* __restrict__ qws, const float* __restrict__ kv,
    __hip_bfloat16* __restrict__ ows) {
    constexpr int KVB = 128;
    __shared__ alignas(16) __hip_bfloat16 Ks[KVB * 72];      // 18432 B
    __shared__ alignas(16) __hip_bfloat16 Vt[64 * KVB];      // 16384 B [d][t^swz]
    __shared__ alignas(16) __hip_bfloat16 Ps[8][16 * 136];   // 34816 B

    const int tid = threadIdx.x;
    const int w = tid >> 6, lane = tid & 63;
    const int g = lane >> 4, lr = lane & 15;
    const int bh = blockIdx.x;            // b*16 + h  (x-fastest: L2/XCD locality)
    const int q0 = blockIdx.y * 128 + w * 16;

    const __hip_bfloat16* qbase = qws + (size_t)bh * Ll * DHh;
    const float* kvb = kv + (size_t)bh * TKV * 128;

    short8 qf[2];
#pragma unroll
    for (int kk = 0; kk < 2; kk++)
        qf[kk] = *(const short8*)(qbase + (size_t)(q0 + lr) * DHh + kk * 32 + g * 8);

    // staging registers (tile in flight): 2 chunks per thread for K and V
    short8 kreg[2], vreg[2];
    const int sc_t[2]   = { (0 * 512 + tid) >> 3, (1 * 512 + tid) >> 3 };
    const int sc_off[2] = { ((0 * 512 + tid) & 7) * 8, ((1 * 512 + tid) & 7) * 8 };

#pragma unroll
    for (int it = 0; it < 2; it++) {
        const float* gp = kvb + (size_t)sc_t[it] * 128;
        kreg[it] = cvt8(gp + sc_off[it]);
        vreg[it] = cvt8(gp + 64 + sc_off[it]);
    }

    float rm[4], rl[4];
    floatx4 o[4] = {};
#pragma unroll
    for (int j = 0; j < 4; j++) { rm[j] = -3e38f; rl[j] = 0.f; }

    for (int t0 = 0; t0 < TKV; t0 += KVB) {
        __syncthreads();   // previous tile fully consumed; LDS free
        // write staged regs -> LDS (K row-major pad 72; V^T XOR-swizzled)
#pragma unroll
        for (int it = 0; it < 2; it++) {
            int t = sc_t[it], off = sc_off[it];
            *(short8*)&Ks[t * 72 + off] = kreg[it];
#pragma unroll
            for (int e = 0; e < 8; e++) {
                int d = off + e;
                int sw = ((d >> 3) ^ d) & 7;
                ((short*)Vt)[d * KVB + (t ^ (sw << 3))] = vreg[it][e];
            }
        }
        __syncthreads();   // LDS ready
        // issue next tile's global loads now; latency hides under compute
        if (t0 + KVB < TKV) {
#pragma unroll
            for (int it = 0; it < 2; it++) {
                const float* gp = kvb + (size_t)(t0 + KVB + sc_t[it]) * 128;
                kreg[it] = cvt8(gp + sc_off[it]);
                vreg[it] = cvt8(gp + 64 + sc_off[it]);
            }
        }

        // S = Q @ K^T (Q pre-scaled): 8 col-blocks of 16 kv each
        floatx4 s[8];
#pragma unroll
        for (int f = 0; f < 8; f++) {
            floatx4 z = {};
#pragma unroll
            for (int kk = 0; kk < 2; kk++) {
                short8 bfr = *(const short8*)&Ks[(f * 16 + lr) * 72 + kk * 32 + g * 8];
                z = MFMA16(qf[kk], bfr, z);
            }
            s[f] = z;
        }

        // online softmax: q-row r = g*4 + j lives on the 16 lanes of group g
        float mt[4];
#pragma unroll
        for (int j = 0; j < 4; j++) {
            float mv = fmaxf(fmaxf(fmaxf(s[0][j], s[1][j]), fmaxf(s[2][j], s[3][j])),
                             fmaxf(fmaxf(s[4][j], s[5][j]), fmaxf(s[6][j], s[7][j])));
            mv = fmaxf(mv, __shfl_xor(mv, 1));
            mv = fmaxf(mv, __shfl_xor(mv, 2));
            mv = fmaxf(mv, __shfl_xor(mv, 4));
            mv = fmaxf(mv, __shfl_xor(mv, 8));
            mt[j] = mv;
        }
        float corr[4];
#pragma unroll
        for (int j = 0; j < 4; j++) {
            float mn = fmaxf(rm[j], mt[j]);
            corr[j] = __expf(rm[j] - mn);
            rm[j] = mn;
        }
        float rs[4] = {0.f, 0.f, 0.f, 0.f};
#pragma unroll
        for (int f = 0; f < 8; f++)
#pragma unroll
            for (int j = 0; j < 4; j++) {
                float p = __expf(s[f][j] - rm[j]);
                s[f][j] = p;
                rs[j] += p;
            }
#pragma unroll
        for (int j = 0; j < 4; j++) {
            rs[j] += __shfl_xor(rs[j], 1);
            rs[j] += __shfl_xor(rs[j], 2);
            rs[j] += __shfl_xor(rs[j], 4);
            rs[j] += __shfl_xor(rs[j], 8);
            rl[j] = rl[j] * corr[j] + rs[j];
#pragma unroll
            for (int f2 = 0; f2 < 4; f2++) o[f2][j] = o[f2][j] * corr[j];
        }

        // P -> LDS (per-wave region)
        __hip_bfloat16* pw = &Ps[w][0];
#pragma unroll
        for (int f = 0; f < 8; f++)
#pragma unroll
            for (int j = 0; j < 4; j++)
                pw[(g * 4 + j) * 136 + f * 16 + lr] = __float2bfloat16(s[f][j]);

        // PV: A = P (rows=q), B = V^T rows (swizzled b128 reads)
#pragma unroll
        for (int kk = 0; kk < 4; kk++) {
            short8 pa = *(const short8*)&pw[lr * 136 + kk * 32 + g * 8];
#pragma unroll
            for (int f2 = 0; f2 < 4; f2++) {
                int d = f2 * 16 + lr;
                int sw = ((d >> 3) ^ d) & 7;
                short8 vb = *(const short8*)&Vt[d * KVB + ((kk * 32 + g * 8) ^ (sw << 3))];
                o[f2] = MFMA16(pa, vb, o[f2]);
            }
        }
    }

    // Epilogue: normalize and store bf16 to (B,L,D) workspace
    const int b = bh >> 4, h = bh & 15;
#pragma unroll
    for (int j = 0; j < 4; j++) {
        float inv = 1.0f / rl[j];
        int qrow = q0 + g * 4 + j;
        size_t rb = ((size_t)b * Ll + qrow) * Dd + (size_t)h * DHh;
#pragma unroll
        for (int f2 = 0; f2 < 4; f2++)
            ows[rb + f2 * 16 + lr] = __float2bfloat16(o[f2][j] * inv);
    }
}

// ---------------------------------------------------------------------------
extern "C" void kernel_launch(void* const* d_in, const int* in_sizes, int n_in,
                              void* d_out, int out_size, void* d_ws, size_t ws_size,
                              hipStream_t stream) {
    (void)in_sizes; (void)n_in; (void)out_size; (void)ws_size;
    const float* query = (const float*)d_in[0];
    const float* key   = (const float*)d_in[1];
    const float* value = (const float*)d_in[2];
    const float* cache = (const float*)d_in[3];
    const float* Wq = (const float*)d_in[4];
    const float* bq = (const float*)d_in[5];
    const float* Wk = (const float*)d_in[6];
    const float* bk = (const float*)d_in[7];
    const float* Wv = (const float*)d_in[8];
    const float* bv = (const float*)d_in[9];
    const float* Wo = (const float*)d_in[10];
    const float* bo = (const float*)d_in[11];

    float* out = (float*)d_out;
    __hip_bfloat16* qws = (__hip_bfloat16*)d_ws;          // (B,H,L,DH) bf16, 8 MB
    __hip_bfloat16* aws = qws + OUT_ELEMS;                // (B,L,D)    bf16, 8 MB

    dim3 bb(256);
    copy_cache_kernel<<<dim3(4096), bb, 0, stream>>>(cache, out);

    dim3 gg(32, 8);
    gemm_nt<1><<<gg, bb, 0, stream>>>(query, Wq, bq, qws);
    gemm_nt<2><<<gg, bb, 0, stream>>>(key, Wk, bk, out);
    gemm_nt<3><<<gg, bb, 0, stream>>>(value, Wv, bv, out);

    attn_kernel<<<dim3(64, 8), dim3(512), 0, stream>>>(qws, out + OUT_ELEMS, aws);

    gemm_nt<0><<<gg, bb, 0, stream>>>(aws, Wo, bo, out);
}

// Round 8
// 225.777 us; speedup vs baseline: 1.4534x; 1.1701x over previous
//
#include <hip/hip_runtime.h>
#include <hip/hip_bf16.h>
#include <stdint.h>

// Problem constants (f32 I/O; bf16 internal compute)
constexpr int Hh = 16, Ll = 1024, Dd = 1024, DHh = 64, CL = 1024, TKV = 2048;
constexpr size_t OUT_ELEMS = 4ull * 1024 * 1024;   // B*L*D = 4,194,304 floats

typedef __attribute__((ext_vector_type(8))) short short8;
typedef __attribute__((ext_vector_type(4))) float floatx4;

#define MFMA16(a, b, c) __builtin_amdgcn_mfma_f32_16x16x32_bf16(a, b, c, 0, 0, 0)

__device__ __forceinline__ short bfs(float x) {
    union { __hip_bfloat16 h; short s; } u;
    u.h = __float2bfloat16(x);
    return u.s;
}

__device__ __forceinline__ short8 cvt8(const float* p) {
    float4 a = *(const float4*)p;
    float4 b = *(const float4*)(p + 4);
    short8 r;
    r[0] = bfs(a.x); r[1] = bfs(a.y); r[2] = bfs(a.z); r[3] = bfs(a.w);
    r[4] = bfs(b.x); r[5] = bfs(b.y); r[6] = bfs(b.z); r[7] = bfs(b.w);
    return r;
}

__device__ __forceinline__ void gload_lds16(const __hip_bfloat16* g, __hip_bfloat16* l) {
    __builtin_amdgcn_global_load_lds((const __attribute__((address_space(1))) void*)g,
                                     (__attribute__((address_space(3))) void*)l, 16, 0, 0);
}

// ---------------------------------------------------------------------------
// Kernel 1: exact f32 copy of old cache into new_cache[t < CL]
// ---------------------------------------------------------------------------
__global__ __launch_bounds__(256) void copy_cache_kernel(
    const float* __restrict__ cache, float* __restrict__ outc) {
    int c = blockIdx.x * 256 + threadIdx.x;   // 1,048,576 chunks of 8 floats
    int bh  = c >> 14;                        // 16384 chunks per (b,h)
    int rem = c & 16383;
    const float* s = cache + (size_t)c * 8;
    float* d = outc + OUT_ELEMS + (size_t)bh * 262144 + (size_t)rem * 8;
    *(float4*)d       = *(const float4*)s;
    *(float4*)(d + 4) = *(const float4*)(s + 4);
}

// ---------------------------------------------------------------------------
// Kernel 2: convert the 4 weight matrices (1024x1024 f32) to bf16 workspace
// ---------------------------------------------------------------------------
__global__ __launch_bounds__(256) void convert_w_kernel(
    const float* __restrict__ Wq, const float* __restrict__ Wk,
    const float* __restrict__ Wv, const float* __restrict__ Wo,
    __hip_bfloat16* __restrict__ Wb) {
    int c = blockIdx.x * 256 + threadIdx.x;   // 524,288 chunks of 8
    int wsel = c >> 17;                        // 131072 chunks per W
    int within = c & 131071;
    const float* src = (wsel == 0) ? Wq : (wsel == 1) ? Wk : (wsel == 2) ? Wv : Wo;
    *(short8*)(Wb + (size_t)c * 8) = cvt8(src + (size_t)within * 8);
}

// ---------------------------------------------------------------------------
// GEMM: C(4096,1024) = A(4096,1024) @ W(1024,1024)^T + bias
// Tile BM=64 x BN=128, BK=64; grid (64,8)=512 blocks (2/CU); 4 waves (2x2),
// wave owns 32x64 (acc[2][4]). B staged via global_load_lds from bf16 Wb.
// MODE 0: A = bf16 ws (attn out, gload_lds), C = f32 d_out[0:OUT_ELEMS]
// MODE 1: A = f32 query (cvt8), C = bf16 Q ws (B,H,L,DH), scaled 1/8
// MODE 2: A = f32 key,   C = f32 new_cache [b,h,CL+l, 0:64]
// MODE 3: A = f32 value, C = f32 new_cache [b,h,CL+l, 64:128]
// ---------------------------------------------------------------------------
template <int MODE>
__global__ __launch_bounds__(256) void gemm_nt(
    const void* __restrict__ Av, const __hip_bfloat16* __restrict__ Wb,
    const float* __restrict__ bias, void* __restrict__ Cv) {
    constexpr int K = 1024, BK = 64;
    __shared__ alignas(16) __hip_bfloat16 As[64 * BK];    //  8 KB
    __shared__ alignas(16) __hip_bfloat16 Bs[128 * BK];   // 16 KB

    const int tid = threadIdx.x;
    const int w = tid >> 6, lane = tid & 63;
    const int g = lane >> 4, lr = lane & 15;
    const int tm = blockIdx.x * 64, tn = blockIdx.y * 128;
    const int wr = (w >> 1) * 32, wc = (w & 1) * 64;

    floatx4 acc[2][4] = {};

    for (int k0 = 0; k0 < K; k0 += BK) {
        __syncthreads();
        // B: 1024 chunks via async global->LDS (bf16 source, zero VALU)
#pragma unroll
        for (int it = 0; it < 4; it++) {
            int c0 = it * 256 + w * 64;
            int c = c0 + lane;
            int row = c >> 3, col = (c & 7) * 8;
            gload_lds16(Wb + (size_t)(tn + row) * K + k0 + col, &Bs[c0 * 8]);
        }
        // A: 512 chunks
#pragma unroll
        for (int it = 0; it < 2; it++) {
            int c0 = it * 256 + w * 64;
            int c = c0 + lane;
            int row = c >> 3, col = (c & 7) * 8;
            if (MODE == 0) {
                gload_lds16((const __hip_bfloat16*)Av + (size_t)(tm + row) * K + k0 + col,
                            &As[c0 * 8]);
            } else {
                *(short8*)&As[c * 8] = cvt8((const float*)Av + (size_t)(tm + row) * K + k0 + col);
            }
        }
        __syncthreads();
#pragma unroll
        for (int kk = 0; kk < 2; kk++) {
            short8 af[2], bf[4];
#pragma unroll
            for (int i = 0; i < 2; i++)
                af[i] = *(const short8*)&As[(wr + i * 16 + lr) * BK + kk * 32 + g * 8];
#pragma unroll
            for (int j = 0; j < 4; j++)
                bf[j] = *(const short8*)&Bs[(wc + j * 16 + lr) * BK + kk * 32 + g * 8];
#pragma unroll
            for (int i = 0; i < 2; i++)
#pragma unroll
                for (int j = 0; j < 4; j++)
                    acc[i][j] = MFMA16(af[i], bf[j], acc[i][j]);
        }
    }

    // Epilogue: bias + mode-specific scatter (f32 except MODE 1 -> bf16 ws)
#pragma unroll
    for (int j = 0; j < 4; j++) {
        int n = tn + wc + j * 16 + lr;
        float bv = bias[n];
#pragma unroll
        for (int i = 0; i < 2; i++) {
#pragma unroll
            for (int r = 0; r < 4; r++) {
                int m = tm + wr + i * 16 + g * 4 + r;
                float v = acc[i][j][r] + bv;
                if (MODE == 0) {
                    ((float*)Cv)[(size_t)m * 1024 + n] = v;
                } else if (MODE == 1) {
                    // fold QK^T 1/sqrt(DH)=1/8 scale into Q (exact: power of 2)
                    size_t addr = (size_t)(m >> 10) * ((size_t)Hh * Ll * DHh) +
                                  (size_t)(n >> 6) * ((size_t)Ll * DHh) +
                                  (size_t)(m & 1023) * DHh + (n & 63);
                    ((__hip_bfloat16*)Cv)[addr] = __float2bfloat16(v * 0.125f);
                } else {
                    size_t bh = (size_t)((m >> 10) * Hh + (n >> 6));
                    size_t addr = OUT_ELEMS + (bh * TKV + CL + (m & 1023)) * 128 + (n & 63) +
                                  (MODE == 3 ? 64 : 0);
                    ((float*)Cv)[addr] = v;
                }
            }
        }
    }
}

// ---------------------------------------------------------------------------
// Flash attention: grid (B*H, L/128), 512 threads = 8 waves, wave owns 16 q-rows.
// KVBLK=128, register-staged double buffer (async-STAGE split).
// K row-major [128][72]; V transposed Vt[d][t^swz] (XOR swizzle).
// Q pre-scaled by 1/8. O -> bf16 ws (B,L,D).
// ---------------------------------------------------------------------------
__global__ __launch_bounds__(512) void attn_kernel(
    const __hip_bfloat16* __restrict__ qws, const float* __restrict__ kv,
    __hip_bfloat16* __restrict__ ows) {
    constexpr int KVB = 128;
    __shared__ alignas(16) __hip_bfloat16 Ks[KVB * 72];      // 18432 B
    __shared__ alignas(16) __hip_bfloat16 Vt[64 * KVB];      // 16384 B [d][t^swz]
    __shared__ alignas(16) __hip_bfloat16 Ps[8][16 * 136];   // 34816 B

    const int tid = threadIdx.x;
    const int w = tid >> 6, lane = tid & 63;
    const int g = lane >> 4, lr = lane & 15;
    const int bh = blockIdx.x;            // b*16 + h  (x-fastest: L2/XCD locality)
    const int q0 = blockIdx.y * 128 + w * 16;

    const __hip_bfloat16* qbase = qws + (size_t)bh * Ll * DHh;
    const float* kvb = kv + (size_t)bh * TKV * 128;

    short8 qf[2];
#pragma unroll
    for (int kk = 0; kk < 2; kk++)
        qf[kk] = *(const short8*)(qbase + (size_t)(q0 + lr) * DHh + kk * 32 + g * 8);

    // staging registers (tile in flight): 2 chunks per thread for K and V
    short8 kreg[2], vreg[2];
    const int sc_t[2]   = { (0 * 512 + tid) >> 3, (1 * 512 + tid) >> 3 };
    const int sc_off[2] = { ((0 * 512 + tid) & 7) * 8, ((1 * 512 + tid) & 7) * 8 };

#pragma unroll
    for (int it = 0; it < 2; it++) {
        const float* gp = kvb + (size_t)sc_t[it] * 128;
        kreg[it] = cvt8(gp + sc_off[it]);
        vreg[it] = cvt8(gp + 64 + sc_off[it]);
    }

    float rm[4], rl[4];
    floatx4 o[4] = {};
#pragma unroll
    for (int j = 0; j < 4; j++) { rm[j] = -3e38f; rl[j] = 0.f; }

    for (int t0 = 0; t0 < TKV; t0 += KVB) {
        __syncthreads();   // previous tile fully consumed; LDS free
        // write staged regs -> LDS (K row-major pad 72; V^T XOR-swizzled)
#pragma unroll
        for (int it = 0; it < 2; it++) {
            int t = sc_t[it], off = sc_off[it];
            *(short8*)&Ks[t * 72 + off] = kreg[it];
#pragma unroll
            for (int e = 0; e < 8; e++) {
                int d = off + e;
                int sw = ((d >> 3) ^ d) & 7;
                ((short*)Vt)[d * KVB + (t ^ (sw << 3))] = vreg[it][e];
            }
        }
        __syncthreads();   // LDS ready
        // issue next tile's global loads now; latency hides under compute
        if (t0 + KVB < TKV) {
#pragma unroll
            for (int it = 0; it < 2; it++) {
                const float* gp = kvb + (size_t)(t0 + KVB + sc_t[it]) * 128;
                kreg[it] = cvt8(gp + sc_off[it]);
                vreg[it] = cvt8(gp + 64 + sc_off[it]);
            }
        }

        // S = Q @ K^T (Q pre-scaled): 8 col-blocks of 16 kv each
        floatx4 s[8];
#pragma unroll
        for (int f = 0; f < 8; f++) {
            floatx4 z = {};
#pragma unroll
            for (int kk = 0; kk < 2; kk++) {
                short8 bfr = *(const short8*)&Ks[(f * 16 + lr) * 72 + kk * 32 + g * 8];
                z = MFMA16(qf[kk], bfr, z);
            }
            s[f] = z;
        }

        // online softmax: q-row r = g*4 + j lives on the 16 lanes of group g
        float mt[4];
#pragma unroll
        for (int j = 0; j < 4; j++) {
            float mv = fmaxf(fmaxf(fmaxf(s[0][j], s[1][j]), fmaxf(s[2][j], s[3][j])),
                             fmaxf(fmaxf(s[4][j], s[5][j]), fmaxf(s[6][j], s[7][j])));
            mv = fmaxf(mv, __shfl_xor(mv, 1));
            mv = fmaxf(mv, __shfl_xor(mv, 2));
            mv = fmaxf(mv, __shfl_xor(mv, 4));
            mv = fmaxf(mv, __shfl_xor(mv, 8));
            mt[j] = mv;
        }
        float corr[4];
#pragma unroll
        for (int j = 0; j < 4; j++) {
            float mn = fmaxf(rm[j], mt[j]);
            corr[j] = __expf(rm[j] - mn);
            rm[j] = mn;
        }
        float rs[4] = {0.f, 0.f, 0.f, 0.f};
#pragma unroll
        for (int f = 0; f < 8; f++)
#pragma unroll
            for (int j = 0; j < 4; j++) {
                float p = __expf(s[f][j] - rm[j]);
                s[f][j] = p;
                rs[j] += p;
            }
#pragma unroll
        for (int j = 0; j < 4; j++) {
            rs[j] += __shfl_xor(rs[j], 1);
            rs[j] += __shfl_xor(rs[j], 2);
            rs[j] += __shfl_xor(rs[j], 4);
            rs[j] += __shfl_xor(rs[j], 8);
            rl[j] = rl[j] * corr[j] + rs[j];
#pragma unroll
            for (int f2 = 0; f2 < 4; f2++) o[f2][j] = o[f2][j] * corr[j];
        }

        // P -> LDS (per-wave region)
        __hip_bfloat16* pw = &Ps[w][0];
#pragma unroll
        for (int f = 0; f < 8; f++)
#pragma unroll
            for (int j = 0; j < 4; j++)
                pw[(g * 4 + j) * 136 + f * 16 + lr] = __float2bfloat16(s[f][j]);

        // PV: A = P (rows=q), B = V^T rows (swizzled b128 reads)
#pragma unroll
        for (int kk = 0; kk < 4; kk++) {
            short8 pa = *(const short8*)&pw[lr * 136 + kk * 32 + g * 8];
#pragma unroll
            for (int f2 = 0; f2 < 4; f2++) {
                int d = f2 * 16 + lr;
                int sw = ((d >> 3) ^ d) & 7;
                short8 vb = *(const short8*)&Vt[d * KVB + ((kk * 32 + g * 8) ^ (sw << 3))];
                o[f2] = MFMA16(pa, vb, o[f2]);
            }
        }
    }

    // Epilogue: normalize and store bf16 to (B,L,D) workspace
    const int b = bh >> 4, h = bh & 15;
#pragma unroll
    for (int j = 0; j < 4; j++) {
        float inv = 1.0f / rl[j];
        int qrow = q0 + g * 4 + j;
        size_t rb = ((size_t)b * Ll + qrow) * Dd + (size_t)h * DHh;
#pragma unroll
        for (int f2 = 0; f2 < 4; f2++)
            ows[rb + f2 * 16 + lr] = __float2bfloat16(o[f2][j] * inv);
    }
}

// ---------------------------------------------------------------------------
extern "C" void kernel_launch(void* const* d_in, const int* in_sizes, int n_in,
                              void* d_out, int out_size, void* d_ws, size_t ws_size,
                              hipStream_t stream) {
    (void)in_sizes; (void)n_in; (void)out_size; (void)ws_size;
    const float* query = (const float*)d_in[0];
    const float* key   = (const float*)d_in[1];
    const float* value = (const float*)d_in[2];
    const float* cache = (const float*)d_in[3];
    const float* Wq = (const float*)d_in[4];
    const float* bq = (const float*)d_in[5];
    const float* Wk = (const float*)d_in[6];
    const float* bk = (const float*)d_in[7];
    const float* Wv = (const float*)d_in[8];
    const float* bv = (const float*)d_in[9];
    const float* Wo = (const float*)d_in[10];
    const float* bo = (const float*)d_in[11];

    float* out = (float*)d_out;
    __hip_bfloat16* qws = (__hip_bfloat16*)d_ws;          // (B,H,L,DH) bf16, 8 MB
    __hip_bfloat16* aws = qws + OUT_ELEMS;                // (B,L,D)    bf16, 8 MB
    __hip_bfloat16* Wb  = aws + OUT_ELEMS;                // 4x (1024x1024) bf16, 8 MB

    dim3 bb(256);
    copy_cache_kernel<<<dim3(4096), bb, 0, stream>>>(cache, out);
    convert_w_kernel<<<dim3(2048), bb, 0, stream>>>(Wq, Wk, Wv, Wo, Wb);

    dim3 gg(64, 8);
    gemm_nt<1><<<gg, bb, 0, stream>>>(query, Wb,               bq, qws);
    gemm_nt<2><<<gg, bb, 0, stream>>>(key,   Wb + (1u << 20),  bk, out);
    gemm_nt<3><<<gg, bb, 0, stream>>>(value, Wb + (2u << 20),  bv, out);

    attn_kernel<<<dim3(64, 8), dim3(512), 0, stream>>>(qws, out + OUT_ELEMS, aws);

    gemm_nt<0><<<gg, bb, 0, stream>>>(aws, Wb + (3u << 20), bo, out);
}

// Round 9
// 223.101 us; speedup vs baseline: 1.4708x; 1.0120x over previous
//
#include <hip/hip_runtime.h>
#include <hip/hip_bf16.h>
#include <stdint.h>

// Problem constants (f32 I/O; bf16 internal compute)
constexpr int Hh = 16, Ll = 1024, Dd = 1024, DHh = 64, CL = 1024, TKV = 2048;
constexpr size_t OUT_ELEMS = 4ull * 1024 * 1024;   // B*L*D = 4,194,304 floats
constexpr float LOG2E = 1.44269504088896340736f;

typedef __attribute__((ext_vector_type(8))) short short8;
typedef __attribute__((ext_vector_type(4))) float floatx4;

#define MFMA16(a, b, c) __builtin_amdgcn_mfma_f32_16x16x32_bf16(a, b, c, 0, 0, 0)

__device__ __forceinline__ short bfs(float x) {
    union { __hip_bfloat16 h; short s; } u;
    u.h = __float2bfloat16(x);
    return u.s;
}

__device__ __forceinline__ short8 cvt8(const float* p) {
    float4 a = *(const float4*)p;
    float4 b = *(const float4*)(p + 4);
    short8 r;
    r[0] = bfs(a.x); r[1] = bfs(a.y); r[2] = bfs(a.z); r[3] = bfs(a.w);
    r[4] = bfs(b.x); r[5] = bfs(b.y); r[6] = bfs(b.z); r[7] = bfs(b.w);
    return r;
}

__device__ __forceinline__ void gload_lds16(const __hip_bfloat16* g, __hip_bfloat16* l) {
    __builtin_amdgcn_global_load_lds((const __attribute__((address_space(1))) void*)g,
                                     (__attribute__((address_space(3))) void*)l, 16, 0, 0);
}

// ---------------------------------------------------------------------------
// Kernel 1: exact f32 copy of old cache into new_cache[t < CL]
// ---------------------------------------------------------------------------
__global__ __launch_bounds__(256) void copy_cache_kernel(
    const float* __restrict__ cache, float* __restrict__ outc) {
    int c = blockIdx.x * 256 + threadIdx.x;   // 1,048,576 chunks of 8 floats
    int bh  = c >> 14;                        // 16384 chunks per (b,h)
    int rem = c & 16383;
    const float* s = cache + (size_t)c * 8;
    float* d = outc + OUT_ELEMS + (size_t)bh * 262144 + (size_t)rem * 8;
    *(float4*)d       = *(const float4*)s;
    *(float4*)(d + 4) = *(const float4*)(s + 4);
}

// ---------------------------------------------------------------------------
// Kernel 2: convert the 4 weight matrices (1024x1024 f32) to bf16 workspace
// ---------------------------------------------------------------------------
__global__ __launch_bounds__(256) void convert_w_kernel(
    const float* __restrict__ Wq, const float* __restrict__ Wk,
    const float* __restrict__ Wv, const float* __restrict__ Wo,
    __hip_bfloat16* __restrict__ Wb) {
    int c = blockIdx.x * 256 + threadIdx.x;   // 524,288 chunks of 8
    int wsel = c >> 17;                        // 131072 chunks per W
    int within = c & 131071;
    const float* src = (wsel == 0) ? Wq : (wsel == 1) ? Wk : (wsel == 2) ? Wv : Wo;
    *(short8*)(Wb + (size_t)c * 8) = cvt8(src + (size_t)within * 8);
}

// ---------------------------------------------------------------------------
// Fused QKV projection GEMM: grid (64,8,3); z selects {Q,K,V}.
// Tile BM=64 x BN=128, BK=64; 4 waves (2x2), wave owns 32x64 (acc[2][4]).
// B staged via global_load_lds from bf16 Wb; A = f32 input via cvt8.
// z=0: C = bf16 Q ws (B,H,L,DH), scaled by 0.125*log2(e)   (exp2-domain QK)
// z=1: C = f32 new_cache [b,h,CL+l, 0:64]
// z=2: C = f32 new_cache [b,h,CL+l, 64:128]
// ---------------------------------------------------------------------------
__global__ __launch_bounds__(256) void gemm_qkv(
    const float* __restrict__ Aq, const float* __restrict__ Ak,
    const float* __restrict__ Av, const __hip_bfloat16* __restrict__ Wb,
    const float* __restrict__ bq, const float* __restrict__ bk,
    const float* __restrict__ bv, __hip_bfloat16* __restrict__ qws,
    float* __restrict__ outc) {
    constexpr int K = 1024, BK = 64;
    __shared__ alignas(16) __hip_bfloat16 As[64 * BK];    //  8 KB
    __shared__ alignas(16) __hip_bfloat16 Bs[128 * BK];   // 16 KB

    const int mode = blockIdx.z;
    const float* A = (mode == 0) ? Aq : (mode == 1) ? Ak : Av;
    const float* bias = (mode == 0) ? bq : (mode == 1) ? bk : bv;
    const __hip_bfloat16* W = Wb + ((size_t)mode << 20);

    const int tid = threadIdx.x;
    const int w = tid >> 6, lane = tid & 63;
    const int g = lane >> 4, lr = lane & 15;
    const int tm = blockIdx.x * 64, tn = blockIdx.y * 128;
    const int wr = (w >> 1) * 32, wc = (w & 1) * 64;

    floatx4 acc[2][4] = {};

    for (int k0 = 0; k0 < K; k0 += BK) {
        __syncthreads();
#pragma unroll
        for (int it = 0; it < 4; it++) {
            int c0 = it * 256 + w * 64;
            int c = c0 + lane;
            int row = c >> 3, col = (c & 7) * 8;
            gload_lds16(W + (size_t)(tn + row) * K + k0 + col, &Bs[c0 * 8]);
        }
#pragma unroll
        for (int it = 0; it < 2; it++) {
            int c = it * 256 + tid;
            int row = c >> 3, col = (c & 7) * 8;
            *(short8*)&As[c * 8] = cvt8(A + (size_t)(tm + row) * K + k0 + col);
        }
        __syncthreads();
#pragma unroll
        for (int kk = 0; kk < 2; kk++) {
            short8 af[2], bf[4];
#pragma unroll
            for (int i = 0; i < 2; i++)
                af[i] = *(const short8*)&As[(wr + i * 16 + lr) * BK + kk * 32 + g * 8];
#pragma unroll
            for (int j = 0; j < 4; j++)
                bf[j] = *(const short8*)&Bs[(wc + j * 16 + lr) * BK + kk * 32 + g * 8];
#pragma unroll
            for (int i = 0; i < 2; i++)
#pragma unroll
                for (int j = 0; j < 4; j++)
                    acc[i][j] = MFMA16(af[i], bf[j], acc[i][j]);
        }
    }

#pragma unroll
    for (int j = 0; j < 4; j++) {
        int n = tn + wc + j * 16 + lr;
        float bv_ = bias[n];
#pragma unroll
        for (int i = 0; i < 2; i++) {
#pragma unroll
            for (int r = 0; r < 4; r++) {
                int m = tm + wr + i * 16 + g * 4 + r;
                float v = acc[i][j][r] + bv_;
                if (mode == 0) {
                    size_t addr = (size_t)(m >> 10) * ((size_t)Hh * Ll * DHh) +
                                  (size_t)(n >> 6) * ((size_t)Ll * DHh) +
                                  (size_t)(m & 1023) * DHh + (n & 63);
                    qws[addr] = __float2bfloat16(v * (0.125f * LOG2E));
                } else {
                    size_t bh = (size_t)((m >> 10) * Hh + (n >> 6));
                    size_t addr = OUT_ELEMS + (bh * TKV + CL + (m & 1023)) * 128 + (n & 63) +
                                  (mode == 2 ? 64 : 0);
                    outc[addr] = v;
                }
            }
        }
    }
}

// ---------------------------------------------------------------------------
// Final projection GEMM: A = bf16 ws (attn out), both sides gload_lds.
// ---------------------------------------------------------------------------
__global__ __launch_bounds__(256) void gemm_out(
    const __hip_bfloat16* __restrict__ A, const __hip_bfloat16* __restrict__ W,
    const float* __restrict__ bias, float* __restrict__ C) {
    constexpr int K = 1024, BK = 64;
    __shared__ alignas(16) __hip_bfloat16 As[64 * BK];
    __shared__ alignas(16) __hip_bfloat16 Bs[128 * BK];

    const int tid = threadIdx.x;
    const int w = tid >> 6, lane = tid & 63;
    const int g = lane >> 4, lr = lane & 15;
    const int tm = blockIdx.x * 64, tn = blockIdx.y * 128;
    const int wr = (w >> 1) * 32, wc = (w & 1) * 64;

    floatx4 acc[2][4] = {};

    for (int k0 = 0; k0 < K; k0 += BK) {
        __syncthreads();
#pragma unroll
        for (int it = 0; it < 4; it++) {
            int c0 = it * 256 + w * 64;
            int c = c0 + lane;
            int row = c >> 3, col = (c & 7) * 8;
            gload_lds16(W + (size_t)(tn + row) * K + k0 + col, &Bs[c0 * 8]);
        }
#pragma unroll
        for (int it = 0; it < 2; it++) {
            int c0 = it * 256 + w * 64;
            int c = c0 + lane;
            int row = c >> 3, col = (c & 7) * 8;
            gload_lds16(A + (size_t)(tm + row) * K + k0 + col, &As[c0 * 8]);
        }
        __syncthreads();
#pragma unroll
        for (int kk = 0; kk < 2; kk++) {
            short8 af[2], bf[4];
#pragma unroll
            for (int i = 0; i < 2; i++)
                af[i] = *(const short8*)&As[(wr + i * 16 + lr) * BK + kk * 32 + g * 8];
#pragma unroll
            for (int j = 0; j < 4; j++)
                bf[j] = *(const short8*)&Bs[(wc + j * 16 + lr) * BK + kk * 32 + g * 8];
#pragma unroll
            for (int i = 0; i < 2; i++)
#pragma unroll
                for (int j = 0; j < 4; j++)
                    acc[i][j] = MFMA16(af[i], bf[j], acc[i][j]);
        }
    }

#pragma unroll
    for (int j = 0; j < 4; j++) {
        int n = tn + wc + j * 16 + lr;
        float bv = bias[n];
#pragma unroll
        for (int i = 0; i < 2; i++)
#pragma unroll
            for (int r = 0; r < 4; r++) {
                int m = tm + wr + i * 16 + g * 4 + r;
                C[(size_t)m * 1024 + n] = acc[i][j][r] + bv;
            }
    }
}

// ---------------------------------------------------------------------------
// Flash attention: grid (B*H, L/128), 512 threads = 8 waves, wave owns 16 q-rows.
// KVBLK=128, register-staged double buffer. exp2-domain softmax (Q pre-scaled
// by 0.125*log2e) with defer-max (THR=8 -> P <= 256). XOR-swizzled V^T.
// ---------------------------------------------------------------------------
__global__ __launch_bounds__(512) void attn_kernel(
    const __hip_bfloat16* __restrict__ qws, const float* __restrict__ kv,
    __hip_bfloat16* __restrict__ ows) {
    constexpr int KVB = 128;
    __shared__ alignas(16) __hip_bfloat16 Ks[KVB * 72];      // 18432 B
    __shared__ alignas(16) __hip_bfloat16 Vt[64 * KVB];      // 16384 B [d][t^swz]
    __shared__ alignas(16) __hip_bfloat16 Ps[8][16 * 136];   // 34816 B

    const int tid = threadIdx.x;
    const int w = tid >> 6, lane = tid & 63;
    const int g = lane >> 4, lr = lane & 15;
    const int bh = blockIdx.x;            // b*16 + h  (x-fastest: L2/XCD locality)
    const int q0 = blockIdx.y * 128 + w * 16;

    const __hip_bfloat16* qbase = qws + (size_t)bh * Ll * DHh;
    const float* kvb = kv + (size_t)bh * TKV * 128;

    short8 qf[2];
#pragma unroll
    for (int kk = 0; kk < 2; kk++)
        qf[kk] = *(const short8*)(qbase + (size_t)(q0 + lr) * DHh + kk * 32 + g * 8);

    // staging registers (tile in flight): 2 chunks per thread for K and V
    short8 kreg[2], vreg[2];
    const int sc_t[2]   = { (0 * 512 + tid) >> 3, (1 * 512 + tid) >> 3 };
    const int sc_off[2] = { ((0 * 512 + tid) & 7) * 8, ((1 * 512 + tid) & 7) * 8 };

#pragma unroll
    for (int it = 0; it < 2; it++) {
        const float* gp = kvb + (size_t)sc_t[it] * 128;
        kreg[it] = cvt8(gp + sc_off[it]);
        vreg[it] = cvt8(gp + 64 + sc_off[it]);
    }

    float rm[4], rl[4];
    floatx4 o[4] = {};
#pragma unroll
    for (int j = 0; j < 4; j++) { rm[j] = -3e38f; rl[j] = 0.f; }

    for (int t0 = 0; t0 < TKV; t0 += KVB) {
        __syncthreads();   // previous tile fully consumed; LDS free
#pragma unroll
        for (int it = 0; it < 2; it++) {
            int t = sc_t[it], off = sc_off[it];
            *(short8*)&Ks[t * 72 + off] = kreg[it];
#pragma unroll
            for (int e = 0; e < 8; e++) {
                int d = off + e;
                int sw = ((d >> 3) ^ d) & 7;
                ((short*)Vt)[d * KVB + (t ^ (sw << 3))] = vreg[it][e];
            }
        }
        __syncthreads();   // LDS ready
        // issue next tile's global loads now; latency hides under compute
        if (t0 + KVB < TKV) {
#pragma unroll
            for (int it = 0; it < 2; it++) {
                const float* gp = kvb + (size_t)(t0 + KVB + sc_t[it]) * 128;
                kreg[it] = cvt8(gp + sc_off[it]);
                vreg[it] = cvt8(gp + 64 + sc_off[it]);
            }
        }

        // S = Q @ K^T (log2-domain: Q pre-scaled by 0.125*log2e)
        floatx4 s[8];
#pragma unroll
        for (int f = 0; f < 8; f++) {
            floatx4 z = {};
#pragma unroll
            for (int kk = 0; kk < 2; kk++) {
                short8 bfr = *(const short8*)&Ks[(f * 16 + lr) * 72 + kk * 32 + g * 8];
                z = MFMA16(qf[kk], bfr, z);
            }
            s[f] = z;
        }

        // online softmax (exp2 domain), defer-max THR=8
        float mt[4];
#pragma unroll
        for (int j = 0; j < 4; j++) {
            float mv = fmaxf(fmaxf(fmaxf(s[0][j], s[1][j]), fmaxf(s[2][j], s[3][j])),
                             fmaxf(fmaxf(s[4][j], s[5][j]), fmaxf(s[6][j], s[7][j])));
            mv = fmaxf(mv, __shfl_xor(mv, 1));
            mv = fmaxf(mv, __shfl_xor(mv, 2));
            mv = fmaxf(mv, __shfl_xor(mv, 4));
            mv = fmaxf(mv, __shfl_xor(mv, 8));
            mt[j] = mv;
        }
        bool ok = (mt[0] - rm[0] <= 8.f) && (mt[1] - rm[1] <= 8.f) &&
                  (mt[2] - rm[2] <= 8.f) && (mt[3] - rm[3] <= 8.f);
        if (!__all(ok)) {
#pragma unroll
            for (int j = 0; j < 4; j++) {
                float mn = fmaxf(rm[j], mt[j]);
                float corr = exp2f(rm[j] - mn);
                rm[j] = mn;
                rl[j] *= corr;
#pragma unroll
                for (int f2 = 0; f2 < 4; f2++) o[f2][j] = o[f2][j] * corr;
            }
        }
        float rs[4] = {0.f, 0.f, 0.f, 0.f};
#pragma unroll
        for (int f = 0; f < 8; f++)
#pragma unroll
            for (int j = 0; j < 4; j++) {
                float p = exp2f(s[f][j] - rm[j]);
                s[f][j] = p;
                rs[j] += p;
            }
#pragma unroll
        for (int j = 0; j < 4; j++) {
            rs[j] += __shfl_xor(rs[j], 1);
            rs[j] += __shfl_xor(rs[j], 2);
            rs[j] += __shfl_xor(rs[j], 4);
            rs[j] += __shfl_xor(rs[j], 8);
            rl[j] += rs[j];
        }

        // P -> LDS (per-wave region)
        __hip_bfloat16* pw = &Ps[w][0];
#pragma unroll
        for (int f = 0; f < 8; f++)
#pragma unroll
            for (int j = 0; j < 4; j++)
                pw[(g * 4 + j) * 136 + f * 16 + lr] = __float2bfloat16(s[f][j]);

        // PV: A = P (rows=q), B = V^T rows (swizzled b128 reads)
#pragma unroll
        for (int kk = 0; kk < 4; kk++) {
            short8 pa = *(const short8*)&pw[lr * 136 + kk * 32 + g * 8];
#pragma unroll
            for (int f2 = 0; f2 < 4; f2++) {
                int d = f2 * 16 + lr;
                int sw = ((d >> 3) ^ d) & 7;
                short8 vb = *(const short8*)&Vt[d * KVB + ((kk * 32 + g * 8) ^ (sw << 3))];
                o[f2] = MFMA16(pa, vb, o[f2]);
            }
        }
    }

    // Epilogue: normalize and store bf16 to (B,L,D) workspace
    const int b = bh >> 4, h = bh & 15;
#pragma unroll
    for (int j = 0; j < 4; j++) {
        float inv = 1.0f / rl[j];
        int qrow = q0 + g * 4 + j;
        size_t rb = ((size_t)b * Ll + qrow) * Dd + (size_t)h * DHh;
#pragma unroll
        for (int f2 = 0; f2 < 4; f2++)
            ows[rb + f2 * 16 + lr] = __float2bfloat16(o[f2][j] * inv);
    }
}

// ---------------------------------------------------------------------------
extern "C" void kernel_launch(void* const* d_in, const int* in_sizes, int n_in,
                              void* d_out, int out_size, void* d_ws, size_t ws_size,
                              hipStream_t stream) {
    (void)in_sizes; (void)n_in; (void)out_size; (void)ws_size;
    const float* query = (const float*)d_in[0];
    const float* key   = (const float*)d_in[1];
    const float* value = (const float*)d_in[2];
    const float* cache = (const float*)d_in[3];
    const float* Wq = (const float*)d_in[4];
    const float* bq = (const float*)d_in[5];
    const float* Wk = (const float*)d_in[6];
    const float* bk = (const float*)d_in[7];
    const float* Wv = (const float*)d_in[8];
    const float* bv = (const float*)d_in[9];
    const float* Wo = (const float*)d_in[10];
    const float* bo = (const float*)d_in[11];

    float* out = (float*)d_out;
    __hip_bfloat16* qws = (__hip_bfloat16*)d_ws;          // (B,H,L,DH) bf16, 8 MB
    __hip_bfloat16* aws = qws + OUT_ELEMS;                // (B,L,D)    bf16, 8 MB
    __hip_bfloat16* Wb  = aws + OUT_ELEMS;                // 4x (1024x1024) bf16, 8 MB

    dim3 bb(256);
    copy_cache_kernel<<<dim3(4096), bb, 0, stream>>>(cache, out);
    convert_w_kernel<<<dim3(2048), bb, 0, stream>>>(Wq, Wk, Wv, Wo, Wb);

    gemm_qkv<<<dim3(64, 8, 3), bb, 0, stream>>>(query, key, value, Wb, bq, bk, bv, qws, out);

    attn_kernel<<<dim3(64, 8), dim3(512), 0, stream>>>(qws, out + OUT_ELEMS, aws);

    gemm_out<<<dim3(64, 8), bb, 0, stream>>>(aws, Wb + (3u << 20), bo, out);
}

// Round 10
// 212.334 us; speedup vs baseline: 1.5454x; 1.0507x over previous
//
#include <hip/hip_runtime.h>
#include <hip/hip_bf16.h>
#include <stdint.h>

// Problem constants (f32 I/O; bf16 internal compute)
constexpr int Hh = 16, Ll = 1024, Dd = 1024, DHh = 64, CL = 1024, TKV = 2048;
constexpr size_t OUT_ELEMS = 4ull * 1024 * 1024;   // B*L*D = 4,194,304 floats
constexpr float LOG2E = 1.44269504088896340736f;

typedef __attribute__((ext_vector_type(8))) short short8;
typedef __attribute__((ext_vector_type(4))) float floatx4;

#define MFMA16(a, b, c) __builtin_amdgcn_mfma_f32_16x16x32_bf16(a, b, c, 0, 0, 0)

// native 2^x (v_exp_f32). exp2f() libm carries range-handling overhead (~6 VALU
// ops vs 1) — measured +5.6pts VALUBusy in round 9.
__device__ __forceinline__ float fexp2(float x) {
#if __has_builtin(__builtin_amdgcn_exp2f)
    return __builtin_amdgcn_exp2f(x);
#else
    float r;
    asm("v_exp_f32 %0, %1" : "=v"(r) : "v"(x));
    return r;
#endif
}

__device__ __forceinline__ short bfs(float x) {
    union { __hip_bfloat16 h; short s; } u;
    u.h = __float2bfloat16(x);
    return u.s;
}

__device__ __forceinline__ short8 cvt8(const float* p) {
    float4 a = *(const float4*)p;
    float4 b = *(const float4*)(p + 4);
    short8 r;
    r[0] = bfs(a.x); r[1] = bfs(a.y); r[2] = bfs(a.z); r[3] = bfs(a.w);
    r[4] = bfs(b.x); r[5] = bfs(b.y); r[6] = bfs(b.z); r[7] = bfs(b.w);
    return r;
}

__device__ __forceinline__ void gload_lds16(const __hip_bfloat16* g, __hip_bfloat16* l) {
    __builtin_amdgcn_global_load_lds((const __attribute__((address_space(1))) void*)g,
                                     (__attribute__((address_space(3))) void*)l, 16, 0, 0);
}

// ---------------------------------------------------------------------------
// Kernel 1: exact f32 copy of old cache into new_cache[t < CL]
// ---------------------------------------------------------------------------
__global__ __launch_bounds__(256) void copy_cache_kernel(
    const float* __restrict__ cache, float* __restrict__ outc) {
    int c = blockIdx.x * 256 + threadIdx.x;   // 1,048,576 chunks of 8 floats
    int bh  = c >> 14;                        // 16384 chunks per (b,h)
    int rem = c & 16383;
    const float* s = cache + (size_t)c * 8;
    float* d = outc + OUT_ELEMS + (size_t)bh * 262144 + (size_t)rem * 8;
    *(float4*)d       = *(const float4*)s;
    *(float4*)(d + 4) = *(const float4*)(s + 4);
}

// ---------------------------------------------------------------------------
// Kernel 2: convert the 4 weight matrices (1024x1024 f32) to bf16 workspace
// ---------------------------------------------------------------------------
__global__ __launch_bounds__(256) void convert_w_kernel(
    const float* __restrict__ Wq, const float* __restrict__ Wk,
    const float* __restrict__ Wv, const float* __restrict__ Wo,
    __hip_bfloat16* __restrict__ Wb) {
    int c = blockIdx.x * 256 + threadIdx.x;   // 524,288 chunks of 8
    int wsel = c >> 17;                        // 131072 chunks per W
    int within = c & 131071;
    const float* src = (wsel == 0) ? Wq : (wsel == 1) ? Wk : (wsel == 2) ? Wv : Wo;
    *(short8*)(Wb + (size_t)c * 8) = cvt8(src + (size_t)within * 8);
}

// ---------------------------------------------------------------------------
// Fused QKV projection GEMM: grid (64,8,3); z selects {Q,K,V}.
// Tile BM=64 x BN=128, BK=64; 4 waves (2x2), wave owns 32x64 (acc[2][4]).
// B staged via global_load_lds from bf16 Wb; A = f32 input via cvt8.
// z=0: C = bf16 Q ws (B,H,L,DH), scaled by 0.125*log2(e)   (exp2-domain QK)
// z=1: C = f32 new_cache [b,h,CL+l, 0:64]
// z=2: C = f32 new_cache [b,h,CL+l, 64:128]
// ---------------------------------------------------------------------------
__global__ __launch_bounds__(256) void gemm_qkv(
    const float* __restrict__ Aq, const float* __restrict__ Ak,
    const float* __restrict__ Av, const __hip_bfloat16* __restrict__ Wb,
    const float* __restrict__ bq, const float* __restrict__ bk,
    const float* __restrict__ bv, __hip_bfloat16* __restrict__ qws,
    float* __restrict__ outc) {
    constexpr int K = 1024, BK = 64;
    __shared__ alignas(16) __hip_bfloat16 As[64 * BK];    //  8 KB
    __shared__ alignas(16) __hip_bfloat16 Bs[128 * BK];   // 16 KB

    const int mode = blockIdx.z;
    const float* A = (mode == 0) ? Aq : (mode == 1) ? Ak : Av;
    const float* bias = (mode == 0) ? bq : (mode == 1) ? bk : bv;
    const __hip_bfloat16* W = Wb + ((size_t)mode << 20);

    const int tid = threadIdx.x;
    const int w = tid >> 6, lane = tid & 63;
    const int g = lane >> 4, lr = lane & 15;
    const int tm = blockIdx.x * 64, tn = blockIdx.y * 128;
    const int wr = (w >> 1) * 32, wc = (w & 1) * 64;

    floatx4 acc[2][4] = {};

    for (int k0 = 0; k0 < K; k0 += BK) {
        __syncthreads();
#pragma unroll
        for (int it = 0; it < 4; it++) {
            int c0 = it * 256 + w * 64;
            int c = c0 + lane;
            int row = c >> 3, col = (c & 7) * 8;
            gload_lds16(W + (size_t)(tn + row) * K + k0 + col, &Bs[c0 * 8]);
        }
#pragma unroll
        for (int it = 0; it < 2; it++) {
            int c = it * 256 + tid;
            int row = c >> 3, col = (c & 7) * 8;
            *(short8*)&As[c * 8] = cvt8(A + (size_t)(tm + row) * K + k0 + col);
        }
        __syncthreads();
#pragma unroll
        for (int kk = 0; kk < 2; kk++) {
            short8 af[2], bf[4];
#pragma unroll
            for (int i = 0; i < 2; i++)
                af[i] = *(const short8*)&As[(wr + i * 16 + lr) * BK + kk * 32 + g * 8];
#pragma unroll
            for (int j = 0; j < 4; j++)
                bf[j] = *(const short8*)&Bs[(wc + j * 16 + lr) * BK + kk * 32 + g * 8];
#pragma unroll
            for (int i = 0; i < 2; i++)
#pragma unroll
                for (int j = 0; j < 4; j++)
                    acc[i][j] = MFMA16(af[i], bf[j], acc[i][j]);
        }
    }

#pragma unroll
    for (int j = 0; j < 4; j++) {
        int n = tn + wc + j * 16 + lr;
        float bv_ = bias[n];
#pragma unroll
        for (int i = 0; i < 2; i++) {
#pragma unroll
            for (int r = 0; r < 4; r++) {
                int m = tm + wr + i * 16 + g * 4 + r;
                float v = acc[i][j][r] + bv_;
                if (mode == 0) {
                    size_t addr = (size_t)(m >> 10) * ((size_t)Hh * Ll * DHh) +
                                  (size_t)(n >> 6) * ((size_t)Ll * DHh) +
                                  (size_t)(m & 1023) * DHh + (n & 63);
                    qws[addr] = __float2bfloat16(v * (0.125f * LOG2E));
                } else {
                    size_t bh = (size_t)((m >> 10) * Hh + (n >> 6));
                    size_t addr = OUT_ELEMS + (bh * TKV + CL + (m & 1023)) * 128 + (n & 63) +
                                  (mode == 2 ? 64 : 0);
                    outc[addr] = v;
                }
            }
        }
    }
}

// ---------------------------------------------------------------------------
// Final projection GEMM: A = bf16 ws (attn out), both sides gload_lds.
// ---------------------------------------------------------------------------
__global__ __launch_bounds__(256) void gemm_out(
    const __hip_bfloat16* __restrict__ A, const __hip_bfloat16* __restrict__ W,
    const float* __restrict__ bias, float* __restrict__ C) {
    constexpr int K = 1024, BK = 64;
    __shared__ alignas(16) __hip_bfloat16 As[64 * BK];
    __shared__ alignas(16) __hip_bfloat16 Bs[128 * BK];

    const int tid = threadIdx.x;
    const int w = tid >> 6, lane = tid & 63;
    const int g = lane >> 4, lr = lane & 15;
    const int tm = blockIdx.x * 64, tn = blockIdx.y * 128;
    const int wr = (w >> 1) * 32, wc = (w & 1) * 64;

    floatx4 acc[2][4] = {};

    for (int k0 = 0; k0 < K; k0 += BK) {
        __syncthreads();
#pragma unroll
        for (int it = 0; it < 4; it++) {
            int c0 = it * 256 + w * 64;
            int c = c0 + lane;
            int row = c >> 3, col = (c & 7) * 8;
            gload_lds16(W + (size_t)(tn + row) * K + k0 + col, &Bs[c0 * 8]);
        }
#pragma unroll
        for (int it = 0; it < 2; it++) {
            int c0 = it * 256 + w * 64;
            int c = c0 + lane;
            int row = c >> 3, col = (c & 7) * 8;
            gload_lds16(A + (size_t)(tm + row) * K + k0 + col, &As[c0 * 8]);
        }
        __syncthreads();
#pragma unroll
        for (int kk = 0; kk < 2; kk++) {
            short8 af[2], bf[4];
#pragma unroll
            for (int i = 0; i < 2; i++)
                af[i] = *(const short8*)&As[(wr + i * 16 + lr) * BK + kk * 32 + g * 8];
#pragma unroll
            for (int j = 0; j < 4; j++)
                bf[j] = *(const short8*)&Bs[(wc + j * 16 + lr) * BK + kk * 32 + g * 8];
#pragma unroll
            for (int i = 0; i < 2; i++)
#pragma unroll
                for (int j = 0; j < 4; j++)
                    acc[i][j] = MFMA16(af[i], bf[j], acc[i][j]);
        }
    }

#pragma unroll
    for (int j = 0; j < 4; j++) {
        int n = tn + wc + j * 16 + lr;
        float bv = bias[n];
#pragma unroll
        for (int i = 0; i < 2; i++)
#pragma unroll
            for (int r = 0; r < 4; r++) {
                int m = tm + wr + i * 16 + g * 4 + r;
                C[(size_t)m * 1024 + n] = acc[i][j][r] + bv;
            }
    }
}

// ---------------------------------------------------------------------------
// Flash attention: grid (B*H, L/128), 512 threads = 8 waves, wave owns 16 q-rows.
// KVBLK=128, register-staged double buffer. exp2-domain softmax (Q pre-scaled
// by 0.125*log2e, native v_exp_f32) with defer-max (THR=8 -> P <= 256).
// XOR-swizzled V^T.
// ---------------------------------------------------------------------------
__global__ __launch_bounds__(512) void attn_kernel(
    const __hip_bfloat16* __restrict__ qws, const float* __restrict__ kv,
    __hip_bfloat16* __restrict__ ows) {
    constexpr int KVB = 128;
    __shared__ alignas(16) __hip_bfloat16 Ks[KVB * 72];      // 18432 B
    __shared__ alignas(16) __hip_bfloat16 Vt[64 * KVB];      // 16384 B [d][t^swz]
    __shared__ alignas(16) __hip_bfloat16 Ps[8][16 * 136];   // 34816 B

    const int tid = threadIdx.x;
    const int w = tid >> 6, lane = tid & 63;
    const int g = lane >> 4, lr = lane & 15;
    const int bh = blockIdx.x;            // b*16 + h  (x-fastest: L2/XCD locality)
    const int q0 = blockIdx.y * 128 + w * 16;

    const __hip_bfloat16* qbase = qws + (size_t)bh * Ll * DHh;
    const float* kvb = kv + (size_t)bh * TKV * 128;

    short8 qf[2];
#pragma unroll
    for (int kk = 0; kk < 2; kk++)
        qf[kk] = *(const short8*)(qbase + (size_t)(q0 + lr) * DHh + kk * 32 + g * 8);

    // staging registers (tile in flight): 2 chunks per thread for K and V
    short8 kreg[2], vreg[2];
    const int sc_t[2]   = { (0 * 512 + tid) >> 3, (1 * 512 + tid) >> 3 };
    const int sc_off[2] = { ((0 * 512 + tid) & 7) * 8, ((1 * 512 + tid) & 7) * 8 };

#pragma unroll
    for (int it = 0; it < 2; it++) {
        const float* gp = kvb + (size_t)sc_t[it] * 128;
        kreg[it] = cvt8(gp + sc_off[it]);
        vreg[it] = cvt8(gp + 64 + sc_off[it]);
    }

    float rm[4], rl[4];
    floatx4 o[4] = {};
#pragma unroll
    for (int j = 0; j < 4; j++) { rm[j] = -3e38f; rl[j] = 0.f; }

    for (int t0 = 0; t0 < TKV; t0 += KVB) {
        __syncthreads();   // previous tile fully consumed; LDS free
#pragma unroll
        for (int it = 0; it < 2; it++) {
            int t = sc_t[it], off = sc_off[it];
            *(short8*)&Ks[t * 72 + off] = kreg[it];
#pragma unroll
            for (int e = 0; e < 8; e++) {
                int d = off + e;
                int sw = ((d >> 3) ^ d) & 7;
                ((short*)Vt)[d * KVB + (t ^ (sw << 3))] = vreg[it][e];
            }
        }
        __syncthreads();   // LDS ready
        // issue next tile's global loads now; latency hides under compute
        if (t0 + KVB < TKV) {
#pragma unroll
            for (int it = 0; it < 2; it++) {
                const float* gp = kvb + (size_t)(t0 + KVB + sc_t[it]) * 128;
                kreg[it] = cvt8(gp + sc_off[it]);
                vreg[it] = cvt8(gp + 64 + sc_off[it]);
            }
        }

        // S = Q @ K^T (log2-domain: Q pre-scaled by 0.125*log2e)
        floatx4 s[8];
#pragma unroll
        for (int f = 0; f < 8; f++) {
            floatx4 z = {};
#pragma unroll
            for (int kk = 0; kk < 2; kk++) {
                short8 bfr = *(const short8*)&Ks[(f * 16 + lr) * 72 + kk * 32 + g * 8];
                z = MFMA16(qf[kk], bfr, z);
            }
            s[f] = z;
        }

        // online softmax (exp2 domain), defer-max THR=8
        float mt[4];
#pragma unroll
        for (int j = 0; j < 4; j++) {
            float mv = fmaxf(fmaxf(fmaxf(s[0][j], s[1][j]), fmaxf(s[2][j], s[3][j])),
                             fmaxf(fmaxf(s[4][j], s[5][j]), fmaxf(s[6][j], s[7][j])));
            mv = fmaxf(mv, __shfl_xor(mv, 1));
            mv = fmaxf(mv, __shfl_xor(mv, 2));
            mv = fmaxf(mv, __shfl_xor(mv, 4));
            mv = fmaxf(mv, __shfl_xor(mv, 8));
            mt[j] = mv;
        }
        bool ok = (mt[0] - rm[0] <= 8.f) && (mt[1] - rm[1] <= 8.f) &&
                  (mt[2] - rm[2] <= 8.f) && (mt[3] - rm[3] <= 8.f);
        if (!__all(ok)) {
#pragma unroll
            for (int j = 0; j < 4; j++) {
                float mn = fmaxf(rm[j], mt[j]);
                float corr = fexp2(rm[j] - mn);
                rm[j] = mn;
                rl[j] *= corr;
#pragma unroll
                for (int f2 = 0; f2 < 4; f2++) o[f2][j] = o[f2][j] * corr;
            }
        }
        float rs[4] = {0.f, 0.f, 0.f, 0.f};
#pragma unroll
        for (int f = 0; f < 8; f++)
#pragma unroll
            for (int j = 0; j < 4; j++) {
                float p = fexp2(s[f][j] - rm[j]);
                s[f][j] = p;
                rs[j] += p;
            }
#pragma unroll
        for (int j = 0; j < 4; j++) {
            rs[j] += __shfl_xor(rs[j], 1);
            rs[j] += __shfl_xor(rs[j], 2);
            rs[j] += __shfl_xor(rs[j], 4);
            rs[j] += __shfl_xor(rs[j], 8);
            rl[j] += rs[j];
        }

        // P -> LDS (per-wave region)
        __hip_bfloat16* pw = &Ps[w][0];
#pragma unroll
        for (int f = 0; f < 8; f++)
#pragma unroll
            for (int j = 0; j < 4; j++)
                pw[(g * 4 + j) * 136 + f * 16 + lr] = __float2bfloat16(s[f][j]);

        // PV: A = P (rows=q), B = V^T rows (swizzled b128 reads)
#pragma unroll
        for (int kk = 0; kk < 4; kk++) {
            short8 pa = *(const short8*)&pw[lr * 136 + kk * 32 + g * 8];
#pragma unroll
            for (int f2 = 0; f2 < 4; f2++) {
                int d = f2 * 16 + lr;
                int sw = ((d >> 3) ^ d) & 7;
                short8 vb = *(const short8*)&Vt[d * KVB + ((kk * 32 + g * 8) ^ (sw << 3))];
                o[f2] = MFMA16(pa, vb, o[f2]);
            }
        }
    }

    // Epilogue: normalize and store bf16 to (B,L,D) workspace
    const int b = bh >> 4, h = bh & 15;
#pragma unroll
    for (int j = 0; j < 4; j++) {
        float inv = 1.0f / rl[j];
        int qrow = q0 + g * 4 + j;
        size_t rb = ((size_t)b * Ll + qrow) * Dd + (size_t)h * DHh;
#pragma unroll
        for (int f2 = 0; f2 < 4; f2++)
            ows[rb + f2 * 16 + lr] = __float2bfloat16(o[f2][j] * inv);
    }
}

// ---------------------------------------------------------------------------
extern "C" void kernel_launch(void* const* d_in, const int* in_sizes, int n_in,
                              void* d_out, int out_size, void* d_ws, size_t ws_size,
                              hipStream_t stream) {
    (void)in_sizes; (void)n_in; (void)out_size; (void)ws_size;
    const float* query = (const float*)d_in[0];
    const float* key   = (const float*)d_in[1];
    const float* value = (const float*)d_in[2];
    const float* cache = (const float*)d_in[3];
    const float* Wq = (const float*)d_in[4];
    const float* bq = (const float*)d_in[5];
    const float* Wk = (const float*)d_in[6];
    const float* bk = (const float*)d_in[7];
    const float* Wv = (const float*)d_in[8];
    const float* bv = (const float*)d_in[9];
    const float* Wo = (const float*)d_in[10];
    const float* bo = (const float*)d_in[11];

    float* out = (float*)d_out;
    __hip_bfloat16* qws = (__hip_bfloat16*)d_ws;          // (B,H,L,DH) bf16, 8 MB
    __hip_bfloat16* aws = qws + OUT_ELEMS;                // (B,L,D)    bf16, 8 MB
    __hip_bfloat16* Wb  = aws + OUT_ELEMS;                // 4x (1024x1024) bf16, 8 MB

    dim3 bb(256);
    copy_cache_kernel<<<dim3(4096), bb, 0, stream>>>(cache, out);
    convert_w_kernel<<<dim3(2048), bb, 0, stream>>>(Wq, Wk, Wv, Wo, Wb);

    gemm_qkv<<<dim3(64, 8, 3), bb, 0, stream>>>(query, key, value, Wb, bq, bk, bv, qws, out);

    attn_kernel<<<dim3(64, 8), dim3(512), 0, stream>>>(qws, out + OUT_ELEMS, aws);

    gemm_out<<<dim3(64, 8), bb, 0, stream>>>(aws, Wb + (3u << 20), bo, out);
}